// Round 3
// baseline (443.528 us; speedup 1.0000x reference)
//
#include <hip/hip_runtime.h>
#include <math.h>

#define NUM_LEVELS 16
#define LEVEL_DIM 2
#define LOG2_T 21
#define TABLE_SIZE (1u << LOG2_T)
#define HASH_MASK (TABLE_SIZE - 1u)
#define N_POINTS 262144
#define BLOCKS_PER_PAIR (N_POINTS / 256)   // 1024

struct ResArgs { float r[NUM_LEVELS]; };

// ---- phase 1: 2 levels per thread, 16 staged gathers for MLP ---------------
__global__ __launch_bounds__(256) void hash_embed_phase1_2lvl(
    const float* __restrict__ x,
    const float* __restrict__ tables,
    float2* __restrict__ ws,      // [NUM_LEVELS][N_POINTS]
    ResArgs res)
{
    const int bid = blockIdx.x;
    const int p  = bid >> 10;                      // level pair 0..7 (slow dim)
    const int l0 = p * 2;
    const int n  = ((bid & (BLOCKS_PER_PAIR - 1)) << 8) + threadIdx.x;

    const float px = x[n * 3 + 0];
    const float py = x[n * 3 + 1];
    const float pz = x[n * 3 + 2];
    const float nx = fminf(fmaxf((px + 2.0f) * 0.25f, 0.0f), 1.0f);
    const float ny = fminf(fmaxf((py + 2.0f) * 0.25f, 0.0f), 1.0f);
    const float nz = fminf(fmaxf((pz + 2.0f) * 0.25f, 0.0f), 1.0f);

    float wxa[2], wya[2], wza[2];
    uint32_t hx0a[2], hy0a[2], hz0a[2];

    #pragma unroll
    for (int lv = 0; lv < 2; ++lv) {
        const float r = res.r[l0 + lv];
        const float sx = nx * r, sy = ny * r, sz = nz * r;
        const float fx = floorf(sx), fy = floorf(sy), fz = floorf(sz);
        wxa[lv] = sx - fx; wya[lv] = sy - fy; wza[lv] = sz - fz;
        hx0a[lv] = (uint32_t)(int)fx * 73856093u;
        hy0a[lv] = (uint32_t)(int)fy * 19349663u;
        hz0a[lv] = (uint32_t)(int)fz * 83492791u;
    }

    // stage all 16 loads before any use -> max memory-level parallelism
    float2 emb[2][8];
    #pragma unroll
    for (int lv = 0; lv < 2; ++lv) {
        const float* __restrict__ tab =
            tables + (size_t)(l0 + lv) * ((size_t)TABLE_SIZE * LEVEL_DIM);
        const uint32_t hx0 = hx0a[lv], hy0 = hy0a[lv], hz0 = hz0a[lv];
        const uint32_t hx1 = hx0 + 73856093u;
        const uint32_t hy1 = hy0 + 19349663u;
        const uint32_t hz1 = hz0 + 83492791u;
        #pragma unroll
        for (int c = 0; c < 8; ++c) {
            const uint32_t hh = ((c & 4) ? hx1 : hx0) ^ ((c & 2) ? hy1 : hy0)
                              ^ ((c & 1) ? hz1 : hz0);
            const uint32_t idx = hh & HASH_MASK;
            emb[lv][c] = *reinterpret_cast<const float2*>(tab + (size_t)idx * LEVEL_DIM);
        }
    }

    #pragma unroll
    for (int lv = 0; lv < 2; ++lv) {
        const float wx = wxa[lv], wy = wya[lv], wz = wza[lv];
        const float ax = 1.0f - wx, ay = 1.0f - wy, az = 1.0f - wz;
        float f0 = 0.0f, f1 = 0.0f;
        #pragma unroll
        for (int c = 0; c < 8; ++c) {
            const float w = (((c & 4) ? wx : ax) * ((c & 2) ? wy : ay))
                          * ((c & 1) ? wz : az);
            f0 = fmaf(w, emb[lv][c].x, f0);
            f1 = fmaf(w, emb[lv][c].y, f1);
        }
        ws[(size_t)(l0 + lv) * N_POINTS + n] = make_float2(f0, f1);
    }
}

// ---- phase 2: transpose ws[l][n] -> out[n][l] ------------------------------
__global__ __launch_bounds__(256) void hash_embed_phase2(
    const float2* __restrict__ ws,
    float2* __restrict__ out)     // out[n][l] as float2
{
    __shared__ float2 tile[64][NUM_LEVELS + 1];
    const int n0 = blockIdx.x * 64;
    const int t = threadIdx.x;
    #pragma unroll
    for (int k = 0; k < 4; ++k) {
        const int e = k * 256 + t;
        const int l = e >> 6;
        const int j = e & 63;
        tile[j][l] = ws[(size_t)l * N_POINTS + n0 + j];
    }
    __syncthreads();
    #pragma unroll
    for (int k = 0; k < 4; ++k) {
        const int e = k * 256 + t;
        const int nl = e >> 4;
        const int l = e & 15;
        out[(size_t)(n0 + nl) * NUM_LEVELS + l] = tile[nl][l];
    }
}

// ---- fallback (R1-proven): interleaved levels, direct out ------------------
__global__ __launch_bounds__(256) void hash_embed_direct(
    const float* __restrict__ x,
    const float* __restrict__ tables,
    float* __restrict__ out,
    ResArgs res)
{
    const int t = blockIdx.x * blockDim.x + threadIdx.x;
    const int n = t >> 4;
    const int l = t & 15;
    if (n >= N_POINTS) return;

    const float px = x[n * 3 + 0];
    const float py = x[n * 3 + 1];
    const float pz = x[n * 3 + 2];
    const float nx = fminf(fmaxf((px + 2.0f) * 0.25f, 0.0f), 1.0f);
    const float ny = fminf(fmaxf((py + 2.0f) * 0.25f, 0.0f), 1.0f);
    const float nz = fminf(fmaxf((pz + 2.0f) * 0.25f, 0.0f), 1.0f);

    const float r = res.r[l];
    const float sx = nx * r, sy = ny * r, sz = nz * r;
    const float fx = floorf(sx), fy = floorf(sy), fz = floorf(sz);
    const float wx = sx - fx, wy = sy - fy, wz = sz - fz;

    const uint32_t hx0 = (uint32_t)(int)fx * 73856093u;
    const uint32_t hy0 = (uint32_t)(int)fy * 19349663u;
    const uint32_t hz0 = (uint32_t)(int)fz * 83492791u;
    const uint32_t hx1 = hx0 + 73856093u;
    const uint32_t hy1 = hy0 + 19349663u;
    const uint32_t hz1 = hz0 + 83492791u;

    const float ax = 1.0f - wx, ay = 1.0f - wy, az = 1.0f - wz;
    const float* __restrict__ tab = tables + (size_t)l * ((size_t)TABLE_SIZE * LEVEL_DIM);

    float f0 = 0.0f, f1 = 0.0f;
    #pragma unroll
    for (int c = 0; c < 8; ++c) {
        const uint32_t hh = ((c & 4) ? hx1 : hx0) ^ ((c & 2) ? hy1 : hy0)
                          ^ ((c & 1) ? hz1 : hz0);
        const uint32_t idx = hh & HASH_MASK;
        const float2 emb = *reinterpret_cast<const float2*>(tab + (size_t)idx * LEVEL_DIM);
        const float w = (((c & 4) ? wx : ax) * ((c & 2) ? wy : ay)) * ((c & 1) ? wz : az);
        f0 = fmaf(w, emb.x, f0);
        f1 = fmaf(w, emb.y, f1);
    }
    float2* o = reinterpret_cast<float2*>(out + (size_t)n * (NUM_LEVELS * LEVEL_DIM) + l * LEVEL_DIM);
    *o = make_float2(f0, f1);
}

extern "C" void kernel_launch(void* const* d_in, const int* in_sizes, int n_in,
                              void* d_out, int out_size, void* d_ws, size_t ws_size,
                              hipStream_t stream) {
    const float* x      = (const float*)d_in[0];
    const float* tables = (const float*)d_in[1];
    float* out          = (float*)d_out;

    ResArgs ra;
    const double b = exp((log(2048.0) - log(16.0)) / 15.0);
    for (int i = 0; i < NUM_LEVELS; ++i) {
        ra.r[i] = (float)floor(16.0 * pow(b, (double)i));
    }

    const size_t ws_needed = (size_t)NUM_LEVELS * N_POINTS * sizeof(float2); // 32 MB
    if (ws_size >= ws_needed) {
        float2* ws = (float2*)d_ws;
        hipLaunchKernelGGL(hash_embed_phase1_2lvl, dim3(8 * BLOCKS_PER_PAIR), dim3(256),
                           0, stream, x, tables, ws, ra);
        hipLaunchKernelGGL(hash_embed_phase2, dim3(N_POINTS / 64), dim3(256),
                           0, stream, ws, (float2*)out);
    } else {
        const int total = N_POINTS * NUM_LEVELS;
        hipLaunchKernelGGL(hash_embed_direct, dim3((total + 255) / 256), dim3(256),
                           0, stream, x, tables, out, ra);
    }
}